// Round 5
// baseline (261.965 us; speedup 1.0000x reference)
//
#include <hip/hip_runtime.h>
#include <hip/hip_bf16.h>

// ---------------------------------------------------------------------------
// GraphAttentionLayer: scores = (x*w_map) @ x^T ; attn = softmax(scores);
// agg = attn @ x ; out = agg@w_att^T + x@w_res^T ; BN(train) ; SELU.
// B=8, N=2048, D=256. All-bf16 MFMA pipeline. No-max softmax (|s| <~ 4).
// R5: k1 S-phase K-fragments read DIRECTLY from global (L2-resident batch
// slab; 16 independent b128 loads/wave streamed into the MFMA chain) --
// deletes the K-tile DMA and 64KB/iter of LDS reads. LDS now holds only the
// double-buffered Vt tile + wave-private P scratch (37KB). One barrier/iter.
// ---------------------------------------------------------------------------

typedef __attribute__((ext_vector_type(8))) short  bf16x8;   // 8 bf16 = 4 VGPRs
typedef __attribute__((ext_vector_type(4))) float  f32x4;

#define MFMA16(a, b, c) __builtin_amdgcn_mfma_f32_16x16x32_bf16((a), (b), (c), 0, 0, 0)

constexpr int   NB = 8, NN = 2048, ND = 256;
constexpr int   ROWS = NB * NN;                 // 16384
constexpr float BN_EPS = 1e-5f;
constexpr float SELU_ALPHA = 1.6732632423543772f;
constexpr float SELU_SCALE = 1.0507009873554805f;

__device__ __forceinline__ unsigned short f2bf(float f) {
  union { float f; unsigned int u; } v; v.f = f;
  unsigned int u = v.u;
  u += 0x7FFFu + ((u >> 16) & 1u);              // round-to-nearest-even
  return (unsigned short)(u >> 16);
}
__device__ __forceinline__ float bf2f(unsigned short h) {
  union { float f; unsigned int u; } v; v.u = ((unsigned int)h) << 16;
  return v.f;
}

// async 16B/lane global->LDS; LDS dest is wave-uniform base + lane*16.
__device__ __forceinline__ void async_copy16(const unsigned short* g, unsigned short* l) {
  __builtin_amdgcn_global_load_lds(
      (const __attribute__((address_space(1))) void*)g,
      (__attribute__((address_space(3))) void*)l, 16, 0, 0);
}

// ---------------------------------------------------------------------------
// k0: x (fp32) -> bf16 into AX right half (row-major) AND Xt (d-major).
// ---------------------------------------------------------------------------
__global__ __launch_bounds__(256) void k0_prep(const float* __restrict__ x,
                                               unsigned short* __restrict__ AX,
                                               unsigned short* __restrict__ Xt) {
  __shared__ unsigned short Ls[64 * 264];
  const int t = threadIdx.x;
  const int b = blockIdx.x & 7, rt = blockIdx.x >> 3;
  const int grb = b * NN + rt * 64;             // global row base
  const int c = (t & 31) * 8, r0 = t >> 5;
#pragma unroll
  for (int q = 0; q < 8; ++q) {
    int r = r0 + q * 8;                         // 64 rows
    const float* xp = x + (size_t)(grb + r) * 256 + c;
    float4 a = *(const float4*)xp;
    float4 d = *(const float4*)(xp + 4);
    union { unsigned short s[8]; uint4 v; } xb;
    xb.s[0] = f2bf(a.x); xb.s[1] = f2bf(a.y); xb.s[2] = f2bf(a.z); xb.s[3] = f2bf(a.w);
    xb.s[4] = f2bf(d.x); xb.s[5] = f2bf(d.y); xb.s[6] = f2bf(d.z); xb.s[7] = f2bf(d.w);
    *(uint4*)(AX + (size_t)(grb + r) * 512 + 256 + c) = xb.v;
    *(uint4*)&Ls[r * 264 + c] = xb.v;
  }
  __syncthreads();
  unsigned short* dst = Xt + ((size_t)b * 256 + t) * 2048 + rt * 64;
#pragma unroll
  for (int k = 0; k < 8; ++k) {
    union { unsigned short s[8]; uint4 v; } o;
#pragma unroll
    for (int j = 0; j < 8; ++j) o.s[j] = Ls[(k * 8 + j) * 264 + t];
    *(uint4*)(dst + k * 8) = o.v;
  }
}

// ---------------------------------------------------------------------------
// k0_wc: WC[c][0:256]=w_att[c], WC[c][256:512]=w_res[c] (bf16). Block 0 zeroes
// the BN-stats accumulator.
// ---------------------------------------------------------------------------
__global__ __launch_bounds__(256) void k0_wc(const float* __restrict__ w_att,
                                             const float* __restrict__ w_res,
                                             unsigned short* __restrict__ WC,
                                             float* __restrict__ sums) {
  if (blockIdx.x == 0 && threadIdx.x < 128)
    ((float4*)sums)[threadIdx.x] = make_float4(0.f, 0.f, 0.f, 0.f);
  int f = (blockIdx.x * 256 + threadIdx.x) * 8;     // < 131072
  int c = f >> 9, k = f & 511;
  const float* src = (k < 256) ? (w_att + c * 256 + k) : (w_res + c * 256 + (k - 256));
  float4 a = *(const float4*)src;
  float4 b = *(const float4*)(src + 4);
  union { unsigned short s[8]; uint4 v; } o;
  o.s[0] = f2bf(a.x); o.s[1] = f2bf(a.y); o.s[2] = f2bf(a.z); o.s[3] = f2bf(a.w);
  o.s[4] = f2bf(b.x); o.s[5] = f2bf(b.y); o.s[6] = f2bf(b.z); o.s[7] = f2bf(b.w);
  *(uint4*)(WC + f) = o.v;
}

// ---------------------------------------------------------------------------
// k1: flash attention, 1 barrier/iter. Block = (batch b, 64 rows), grid 256,
// 4 waves; each wave owns 16 query rows end-to-end.
// S^T = K Q^T with A=kf loaded DIRECTLY from global AX (L2-resident; 16
// independent b128 loads per wave, consumed by the MFMA chain via partial
// vmcnt waits). C col = query row = lane&15 -> P is wave-private.
// P: exp in-reg, pack 4xbf16, ds_write_b64 x2 into per-wave scratch,
// read back as PV A-frag b128 (lgkm-ordered only, no barrier).
// PV: B=vf from LDS Vt [d][j] (chunk swizzle c^((d>>1)&3)), 16 independent
// MFMAs + ones-column MFMA for L. Vt double-buffered via global_load_lds.
// ---------------------------------------------------------------------------
__global__ __launch_bounds__(256, 1) void k1_attn(const float* __restrict__ w_map,
                                                  const unsigned short* AX,
                                                  const unsigned short* __restrict__ Xt,
                                                  unsigned short* AXw) {
  __shared__ unsigned short Vt[2][256 * 32];   // 16 KB each
  __shared__ unsigned short Psw[4][16 * 40];   // per-wave P scratch, 5 KB

  const int t = threadIdx.x;
  const int w = t >> 6, lane = t & 63, l15 = lane & 15, quad = lane >> 4;
  const int b = blockIdx.x & 7, it = blockIdx.x >> 3;
  const int gib = b * NN + it * 64;
  const unsigned short* Xtb = Xt + (size_t)b * 256 * 2048;
  const unsigned short* AXr = AX + (size_t)b * NN * 512 + 256;  // + row*512

  // ---- per-lane V DMA source offsets (element units) ----
  int vtOff[4];
#pragma unroll
  for (int q = 0; q < 4; ++q) {
    int d = w * 64 + q * 16 + (lane >> 2);
    int cv = (lane & 3) ^ ((d >> 1) & 3);
    vtOff[q] = d * 2048 + cv * 8;
  }
  const int ldsOff = w * 2048 + lane * 8;                // ushort units

  // ---- global K-fragment base: addr = kbase + j*512 + kc*32 ----
  const unsigned short* kbase = AXr + (size_t)l15 * 512 + quad * 8;

  // ---- Q B-fragments for the wave's 16 rows (scaled by w_map) ----
  bf16x8 qf[8];
  {
    const unsigned short* xrow = AXr + (size_t)(it * 64 + w * 16 + l15) * 512;
#pragma unroll
    for (int kc = 0; kc < 8; ++kc) {
      bf16x8 xb = *(const bf16x8*)(xrow + kc * 32 + quad * 8);
      const float* wp = w_map + kc * 32 + quad * 8;
      float4 w0 = *(const float4*)wp, w1 = *(const float4*)(wp + 4);
      float wv[8] = {w0.x, w0.y, w0.z, w0.w, w1.x, w1.y, w1.z, w1.w};
      bf16x8 q;
#pragma unroll
      for (int i = 0; i < 8; ++i)
        q[i] = (short)f2bf(bf2f((unsigned short)xb[i]) * wv[i]);
      qf[kc] = q;
    }
  }

  const f32x4 fz = {0.f, 0.f, 0.f, 0.f};
  f32x4 oacc[16];
#pragma unroll
  for (int i = 0; i < 16; ++i) oacc[i] = fz;
  f32x4 oL = fz;

  bf16x8 onesFrag;
  {
    short o1 = (l15 == 0) ? (short)0x3F80 : (short)0;    // bf16 1.0, col 0
#pragma unroll
    for (int i = 0; i < 8; ++i) onesFrag[i] = o1;
  }

  // prologue: stage V tile 0 into buffer 0
#pragma unroll
  for (int q = 0; q < 4; ++q)
    async_copy16(Xtb + vtOff[q], &Vt[0][ldsOff + q * 512]);

  for (int jt = 0; jt < 64; ++jt) {
    const int cur = jt & 1;
    __syncthreads();            // Vt[cur] landed; prev-iter Vt[cur^1] reads done
    if (jt < 63) {              // V prefetch for jt+1, drains at NEXT barrier
      const int jb1 = (jt + 1) * 32;
#pragma unroll
      for (int q = 0; q < 4; ++q)
        async_copy16(Xtb + jb1 + vtOff[q], &Vt[cur ^ 1][ldsOff + q * 512]);
    }
    const int jb = jt * 32;
    // ---- S^T = K Q^T, two m-tiles; kf direct from global (L2) ----
#pragma unroll
    for (int jm = 0; jm < 2; ++jm) {
      const unsigned short* kp = kbase + (size_t)(jb + jm * 16) * 512;
      bf16x8 kf[8];
#pragma unroll
      for (int kc = 0; kc < 8; ++kc)
        kf[kc] = *(const bf16x8*)(kp + kc * 32);
      f32x4 s = fz;
#pragma unroll
      for (int kc = 0; kc < 8; ++kc)
        s = MFMA16(kf[kc], qf[kc], s);
      ushort4 pk;
      pk.x = f2bf(__expf(s[0])); pk.y = f2bf(__expf(s[1]));
      pk.z = f2bf(__expf(s[2])); pk.w = f2bf(__expf(s[3]));
      *(ushort4*)&Psw[w][l15 * 40 + jm * 16 + quad * 4] = pk;   // ds_write_b64
    }
    // ---- PV: A-frag from wave-private scratch (lgkm-ordered, no barrier) --
    bf16x8 af = *(const bf16x8*)&Psw[w][l15 * 40 + quad * 8];
#pragma unroll
    for (int nti = 0; nti < 16; ++nti) {
      const int d = nti * 16 + l15;
      bf16x8 vf = *(const bf16x8*)&Vt[cur][d * 32 + ((quad ^ ((d >> 1) & 3)) * 8)];
      oacc[nti] = MFMA16(af, vf, oacc[nti]);
    }
    oL = MFMA16(af, onesFrag, oL);
  }

  // ---- L broadcast (col-0 lanes hold rows quad*4+r) and write-out ----
  float li[4];
#pragma unroll
  for (int r = 0; r < 4; ++r)
    li[r] = 1.0f / __shfl(oL[r], lane & 48);
#pragma unroll
  for (int nti = 0; nti < 16; ++nti) {
    const int gcol = nti * 16 + l15;
#pragma unroll
    for (int r = 0; r < 4; ++r) {
      const int grow = gib + w * 16 + quad * 4 + r;
      AXw[(size_t)grow * 512 + gcol] = f2bf(oacc[nti][r] * li[r]);
    }
  }
}

// ---------------------------------------------------------------------------
// k2: out_pre = AX @ WC^T  (M=16384, N=256, K=512) == agg@w_att^T + x@w_res^T.
// Block tile 128x64, 4 waves (wave tile 64x32), BK=64, grid 512.
// Epilogue: per-column BN partial sums from acc regs (shfl + LDS + atomics).
// ---------------------------------------------------------------------------
__global__ __launch_bounds__(256, 2) void k2_gemm(const unsigned short* __restrict__ AX,
                                                  const unsigned short* __restrict__ WC,
                                                  float* __restrict__ out,
                                                  float* __restrict__ sums) {
  __shared__ unsigned short As[128 * 72];
  __shared__ unsigned short Bs[64 * 72];
  __shared__ float cs[64], cq[64];
  const int t = threadIdx.x;
  const int w = t >> 6, lane = t & 63, l15 = lane & 15, quad = lane >> 4;
  const int m0 = (blockIdx.x >> 2) * 128, n0 = (blockIdx.x & 3) * 64;
  if (t < 64) { cs[t] = 0.f; cq[t] = 0.f; }

  const f32x4 fz = {0.f, 0.f, 0.f, 0.f};
  f32x4 acc[4][2];
#pragma unroll
  for (int i = 0; i < 4; ++i) { acc[i][0] = fz; acc[i][1] = fz; }

  for (int kk = 0; kk < 512; kk += 64) {
    __syncthreads();
#pragma unroll
    for (int q = 0; q < 4; ++q) {            // A: 128 rows x 64 k
      int idx = t + q * 256;
      int row = idx >> 3, koff = (idx & 7) * 8;
      *(uint4*)&As[row * 72 + koff] = *(const uint4*)(AX + (size_t)(m0 + row) * 512 + kk + koff);
    }
#pragma unroll
    for (int q = 0; q < 2; ++q) {            // B: 64 rows x 64 k
      int idx = t + q * 256;
      int row = idx >> 3, koff = (idx & 7) * 8;
      *(uint4*)&Bs[row * 72 + koff] = *(const uint4*)(WC + (size_t)(n0 + row) * 512 + kk + koff);
    }
    __syncthreads();
#pragma unroll
    for (int kc = 0; kc < 2; ++kc) {
      bf16x8 b0 = *(const bf16x8*)&Bs[((w >> 1) * 32 + l15) * 72 + kc * 32 + quad * 8];
      bf16x8 b1 = *(const bf16x8*)&Bs[((w >> 1) * 32 + 16 + l15) * 72 + kc * 32 + quad * 8];
#pragma unroll
      for (int mt = 0; mt < 4; ++mt) {
        bf16x8 af = *(const bf16x8*)&As[((w & 1) * 64 + mt * 16 + l15) * 72 + kc * 32 + quad * 8];
        acc[mt][0] = MFMA16(af, b0, acc[mt][0]);
        acc[mt][1] = MFMA16(af, b1, acc[mt][1]);
      }
    }
  }
#pragma unroll
  for (int mt = 0; mt < 4; ++mt)
#pragma unroll
    for (int nt = 0; nt < 2; ++nt)
#pragma unroll
      for (int r = 0; r < 4; ++r) {
        int grow = m0 + (w & 1) * 64 + mt * 16 + quad * 4 + r;
        int gcol = n0 + (w >> 1) * 32 + nt * 16 + l15;
        out[(size_t)grow * 256 + gcol] = acc[mt][nt][r];
      }
  // ---- fused BN partial stats: sum / sumsq per column ----
#pragma unroll
  for (int nt = 0; nt < 2; ++nt) {
    float a = 0.f, b2 = 0.f;
#pragma unroll
    for (int mt = 0; mt < 4; ++mt)
#pragma unroll
      for (int r = 0; r < 4; ++r) {
        float v = acc[mt][nt][r];
        a += v; b2 += v * v;
      }
    a += __shfl_xor(a, 16);  a += __shfl_xor(a, 32);
    b2 += __shfl_xor(b2, 16); b2 += __shfl_xor(b2, 32);
    if (quad == 0) {
      int ci = (w >> 1) * 32 + nt * 16 + l15;
      atomicAdd(&cs[ci], a);
      atomicAdd(&cq[ci], b2);
    }
  }
  __syncthreads();
  if (t < 64) {
    atomicAdd(&sums[n0 + t], cs[t]);
    atomicAdd(&sums[256 + n0 + t], cq[t]);
  }
}

// ---------------------------------------------------------------------------
// k4: BatchNorm (biased var) + SELU, in place on d_out.
// ---------------------------------------------------------------------------
__global__ __launch_bounds__(256) void k4_bn_selu(float* __restrict__ out,
                                                  const float* __restrict__ sums,
                                                  const float* __restrict__ gamma,
                                                  const float* __restrict__ beta) {
  int f = (blockIdx.x * 256 + threadIdx.x) * 8;
  int c = f & 255;
  const float inv_m = 1.0f / 16384.0f;
  float4 v0 = *(const float4*)(out + f);
  float4 v1 = *(const float4*)(out + f + 4);
  float vv[8] = {v0.x, v0.y, v0.z, v0.w, v1.x, v1.y, v1.z, v1.w};
#pragma unroll
  for (int k = 0; k < 8; ++k) {
    int ch = c + k;
    float mean = sums[ch] * inv_m;
    float var = sums[256 + ch] * inv_m - mean * mean;
    float y = (vv[k] - mean) * rsqrtf(var + BN_EPS) * gamma[ch] + beta[ch];
    float yc = fminf(fmaxf(y, -10.f), 10.f);
    float r = (y > 0.f) ? y : (SELU_ALPHA * (expf(yc) - 1.0f));
    vv[k] = SELU_SCALE * r;
  }
  float4 o0 = {vv[0], vv[1], vv[2], vv[3]};
  float4 o1 = {vv[4], vv[5], vv[6], vv[7]};
  *(float4*)(out + f) = o0;
  *(float4*)(out + f + 4) = o1;
}

// ---------------------------------------------------------------------------
extern "C" void kernel_launch(void* const* d_in, const int* in_sizes, int n_in,
                              void* d_out, int out_size, void* d_ws, size_t ws_size,
                              hipStream_t stream) {
  const float* x     = (const float*)d_in[0];
  const float* w_map = (const float*)d_in[1];
  const float* w_att = (const float*)d_in[2];
  const float* w_res = (const float*)d_in[3];
  const float* gamma = (const float*)d_in[4];
  const float* beta  = (const float*)d_in[5];
  float* out = (float*)d_out;

  // ws layout (~24.3 MB): AX 16MB | Xt 8MB | WC 256KB | sums 2KB
  unsigned short* AX = (unsigned short*)d_ws;
  unsigned short* Xt = AX + (size_t)ROWS * 512;
  unsigned short* WC = Xt + (size_t)NB * 256 * 2048;
  float* sums = (float*)(WC + 256 * 512);

  k0_prep<<<256, 256, 0, stream>>>(x, AX, Xt);
  k0_wc<<<64, 256, 0, stream>>>(w_att, w_res, WC, sums);
  k1_attn<<<256, 256, 0, stream>>>(w_map, AX, Xt, AX);
  k2_gemm<<<512, 256, 0, stream>>>(AX, WC, out, sums);
  k4_bn_selu<<<2048, 256, 0, stream>>>(out, sums, gamma, beta);
}

// Round 6
// 163.011 us; speedup vs baseline: 1.6070x; 1.6070x over previous
//
#include <hip/hip_runtime.h>
#include <hip/hip_bf16.h>

// ---------------------------------------------------------------------------
// GraphAttentionLayer: scores = (x*w_map) @ x^T ; attn = softmax(scores);
// agg = attn @ x ; out = agg@w_att^T + x@w_res^T ; BN(train) ; SELU.
// B=8, N=2048, D=256. All-bf16 MFMA pipeline. No-max softmax (|s| <~ 4).
// R6: k1 = R4 structure (LDS-staged K+V, 1 barrier/iter, wave-private P)
// but 512 threads: two wave-GROUPS split the j-range (each 32 iters, own
// K/V double-buffers) -> 2 waves/SIMD co-resident to overlap the per-iter
// latency chain. Partials combined through LDS at the end.
// R5 lesson: never mix latency-critical VGPR global loads with async DMA in
// the same loop (shared in-order vmcnt drains the prefetch).
// ---------------------------------------------------------------------------

typedef __attribute__((ext_vector_type(8))) short  bf16x8;   // 8 bf16 = 4 VGPRs
typedef __attribute__((ext_vector_type(4))) float  f32x4;

#define MFMA16(a, b, c) __builtin_amdgcn_mfma_f32_16x16x32_bf16((a), (b), (c), 0, 0, 0)

constexpr int   NB = 8, NN = 2048, ND = 256;
constexpr int   ROWS = NB * NN;                 // 16384
constexpr float BN_EPS = 1e-5f;
constexpr float SELU_ALPHA = 1.6732632423543772f;
constexpr float SELU_SCALE = 1.0507009873554805f;

__device__ __forceinline__ unsigned short f2bf(float f) {
  union { float f; unsigned int u; } v; v.f = f;
  unsigned int u = v.u;
  u += 0x7FFFu + ((u >> 16) & 1u);              // round-to-nearest-even
  return (unsigned short)(u >> 16);
}
__device__ __forceinline__ float bf2f(unsigned short h) {
  union { float f; unsigned int u; } v; v.u = ((unsigned int)h) << 16;
  return v.f;
}

// async 16B/lane global->LDS; LDS dest is wave-uniform base + lane*16.
__device__ __forceinline__ void async_copy16(const unsigned short* g, unsigned short* l) {
  __builtin_amdgcn_global_load_lds(
      (const __attribute__((address_space(1))) void*)g,
      (__attribute__((address_space(3))) void*)l, 16, 0, 0);
}

// ---------------------------------------------------------------------------
// k0: x (fp32) -> bf16 into AX right half (row-major) AND Xt (d-major).
// ---------------------------------------------------------------------------
__global__ __launch_bounds__(256) void k0_prep(const float* __restrict__ x,
                                               unsigned short* __restrict__ AX,
                                               unsigned short* __restrict__ Xt) {
  __shared__ unsigned short Ls[64 * 264];
  const int t = threadIdx.x;
  const int b = blockIdx.x & 7, rt = blockIdx.x >> 3;
  const int grb = b * NN + rt * 64;             // global row base
  const int c = (t & 31) * 8, r0 = t >> 5;
#pragma unroll
  for (int q = 0; q < 8; ++q) {
    int r = r0 + q * 8;                         // 64 rows
    const float* xp = x + (size_t)(grb + r) * 256 + c;
    float4 a = *(const float4*)xp;
    float4 d = *(const float4*)(xp + 4);
    union { unsigned short s[8]; uint4 v; } xb;
    xb.s[0] = f2bf(a.x); xb.s[1] = f2bf(a.y); xb.s[2] = f2bf(a.z); xb.s[3] = f2bf(a.w);
    xb.s[4] = f2bf(d.x); xb.s[5] = f2bf(d.y); xb.s[6] = f2bf(d.z); xb.s[7] = f2bf(d.w);
    *(uint4*)(AX + (size_t)(grb + r) * 512 + 256 + c) = xb.v;
    *(uint4*)&Ls[r * 264 + c] = xb.v;
  }
  __syncthreads();
  unsigned short* dst = Xt + ((size_t)b * 256 + t) * 2048 + rt * 64;
#pragma unroll
  for (int k = 0; k < 8; ++k) {
    union { unsigned short s[8]; uint4 v; } o;
#pragma unroll
    for (int j = 0; j < 8; ++j) o.s[j] = Ls[(k * 8 + j) * 264 + t];
    *(uint4*)(dst + k * 8) = o.v;
  }
}

// ---------------------------------------------------------------------------
// k0_wc: WC[c][0:256]=w_att[c], WC[c][256:512]=w_res[c] (bf16). Block 0 zeroes
// the BN-stats accumulator.
// ---------------------------------------------------------------------------
__global__ __launch_bounds__(256) void k0_wc(const float* __restrict__ w_att,
                                             const float* __restrict__ w_res,
                                             unsigned short* __restrict__ WC,
                                             float* __restrict__ sums) {
  if (blockIdx.x == 0 && threadIdx.x < 128)
    ((float4*)sums)[threadIdx.x] = make_float4(0.f, 0.f, 0.f, 0.f);
  int f = (blockIdx.x * 256 + threadIdx.x) * 8;     // < 131072
  int c = f >> 9, k = f & 511;
  const float* src = (k < 256) ? (w_att + c * 256 + k) : (w_res + c * 256 + (k - 256));
  float4 a = *(const float4*)src;
  float4 b = *(const float4*)(src + 4);
  union { unsigned short s[8]; uint4 v; } o;
  o.s[0] = f2bf(a.x); o.s[1] = f2bf(a.y); o.s[2] = f2bf(a.z); o.s[3] = f2bf(a.w);
  o.s[4] = f2bf(b.x); o.s[5] = f2bf(b.y); o.s[6] = f2bf(b.z); o.s[7] = f2bf(b.w);
  *(uint4*)(WC + f) = o.v;
}

// ---------------------------------------------------------------------------
// k1: flash attention. Block = (batch b, 64 rows), grid 256, 512 threads.
// Wave-group g = w>>2 handles j in [g*1024,(g+1)*1024): 32 iters, own K/V
// double-buffers. Wave wg=w&3 owns query rows wg*16..+15 end-to-end.
// S^T = K Q^T (A=kf from LDS, B=qf regs) -> C col = query row (wave-private
// P). P: exp, pack, 2x ds_write_b64 into per-wave scratch, read back as PV
// A-frag (lgkm-ordered; no second barrier). PV: 16 indep MFMAs + ones-MFMA
// for L. Epilogue: group 1 parks O/L partials in dead K-buffer LDS (quad
// chunk-swizzle -> 2-way max), group 0 combines, normalizes, writes.
// ---------------------------------------------------------------------------
__global__ __launch_bounds__(512, 2) void k1_attn(const float* __restrict__ w_map,
                                                  const unsigned short* AX,
                                                  const unsigned short* __restrict__ Xt,
                                                  unsigned short* AXw) {
  __shared__ unsigned short Ks[2][2][32 * 256];   // [group][buf] 16 KB each
  __shared__ unsigned short Vt[2][2][256 * 32];   // [group][buf] 16 KB each
  __shared__ unsigned short Psw[8][16 * 40];      // per-wave P scratch

  const int t = threadIdx.x;
  const int w = t >> 6, lane = t & 63, l15 = lane & 15, quad = lane >> 4;
  const int g = w >> 2, wg = w & 3;
  const int b = blockIdx.x & 7, it = blockIdx.x >> 3;
  const int gib = b * NN + it * 64;
  const unsigned short* Xtb = Xt + (size_t)b * 256 * 2048;
  const unsigned short* AXr = AX + (size_t)b * NN * 512 + 256;  // + row*512
  const int jgbase = g * 1024;                    // group's j range base

  // ---- per-lane DMA source offsets (element units, within a j-tile) ----
  int ksOff[4], vtOff[4];
#pragma unroll
  for (int q = 0; q < 4; ++q) {
    int j = wg * 8 + q * 2 + (lane >> 5);
    int ck = (lane & 31) ^ (j & 7);               // K chunk swizzle
    ksOff[q] = j * 512 + ck * 8;
    int d = wg * 64 + q * 16 + (lane >> 2);
    int cv = (lane & 3) ^ ((d >> 1) & 3);         // V chunk swizzle
    vtOff[q] = d * 2048 + cv * 8;
  }
  const int ldsOff = wg * 2048 + lane * 8;        // ushort units, per buffer

  // ---- Q B-fragments for the wave's 16 rows (scaled by w_map) ----
  bf16x8 qf[8];
  {
    const unsigned short* xrow = AXr + (size_t)(it * 64 + wg * 16 + l15) * 512;
#pragma unroll
    for (int kc = 0; kc < 8; ++kc) {
      bf16x8 xb = *(const bf16x8*)(xrow + kc * 32 + quad * 8);
      const float* wp = w_map + kc * 32 + quad * 8;
      float4 w0 = *(const float4*)wp, w1 = *(const float4*)(wp + 4);
      float wv[8] = {w0.x, w0.y, w0.z, w0.w, w1.x, w1.y, w1.z, w1.w};
      bf16x8 q;
#pragma unroll
      for (int i = 0; i < 8; ++i)
        q[i] = (short)f2bf(bf2f((unsigned short)xb[i]) * wv[i]);
      qf[kc] = q;
    }
  }

  const f32x4 fz = {0.f, 0.f, 0.f, 0.f};
  f32x4 oacc[16];
#pragma unroll
  for (int i = 0; i < 16; ++i) oacc[i] = fz;
  f32x4 oL = fz;

  bf16x8 onesFrag;
  {
    short o1 = (l15 == 0) ? (short)0x3F80 : (short)0;    // bf16 1.0, col 0
#pragma unroll
    for (int i = 0; i < 8; ++i) onesFrag[i] = o1;
  }

  // prologue: stage this group's tile 0 into buffer 0
#pragma unroll
  for (int q = 0; q < 4; ++q)
    async_copy16(AXr + (size_t)jgbase * 512 + ksOff[q], &Ks[g][0][ldsOff + q * 512]);
#pragma unroll
  for (int q = 0; q < 4; ++q)
    async_copy16(Xtb + jgbase + vtOff[q], &Vt[g][0][ldsOff + q * 512]);

  for (int jt = 0; jt < 32; ++jt) {
    const int cur = jt & 1;
    __syncthreads();            // buf[cur] landed; prev-iter buf[cur^1] reads done
    if (jt < 31) {              // prefetch jt+1, drains at NEXT barrier
      const int jb1 = jgbase + (jt + 1) * 32;
#pragma unroll
      for (int q = 0; q < 4; ++q)
        async_copy16(AXr + (size_t)jb1 * 512 + ksOff[q], &Ks[g][cur ^ 1][ldsOff + q * 512]);
#pragma unroll
      for (int q = 0; q < 4; ++q)
        async_copy16(Xtb + jb1 + vtOff[q], &Vt[g][cur ^ 1][ldsOff + q * 512]);
    }
    // ---- S^T = K Q^T, two m-tiles (j = jm*16 + l15); exp -> Psw ----
#pragma unroll
    for (int jm = 0; jm < 2; ++jm) {
      const int j = jm * 16 + l15;
      f32x4 s = fz;
#pragma unroll
      for (int kc = 0; kc < 8; ++kc) {
        int ckk = kc * 4 + quad;
        bf16x8 kf = *(const bf16x8*)&Ks[g][cur][j * 256 + ((ckk ^ (j & 7)) * 8)];
        s = MFMA16(kf, qf[kc], s);
      }
      ushort4 pk;
      pk.x = f2bf(__expf(s[0])); pk.y = f2bf(__expf(s[1]));
      pk.z = f2bf(__expf(s[2])); pk.w = f2bf(__expf(s[3]));
      *(ushort4*)&Psw[w][l15 * 40 + jm * 16 + quad * 4] = pk;   // ds_write_b64
    }
    // ---- PV: A-frag from wave-private scratch (lgkm-ordered, no barrier) --
    bf16x8 af = *(const bf16x8*)&Psw[w][l15 * 40 + quad * 8];
#pragma unroll
    for (int nti = 0; nti < 16; ++nti) {
      const int d = nti * 16 + l15;
      bf16x8 vf = *(const bf16x8*)&Vt[g][cur][d * 32 + ((quad ^ ((d >> 1) & 3)) * 8)];
      oacc[nti] = MFMA16(af, vf, oacc[nti]);
    }
    oL = MFMA16(af, onesFrag, oL);
  }

  // ---- combine the two groups' partial O and L through dead LDS ----
  __syncthreads();                                 // everyone done with tiles
  float* Obuf = (float*)&Ks[0][0][0];              // 64 KB: [wg][16][256] words
  float* Lb   = (float*)&Vt[0][0][0];              // [wg][16]
  if (g == 1) {
#pragma unroll
    for (int nti = 0; nti < 16; ++nti)
#pragma unroll
      for (int r = 0; r < 4; ++r) {
        int row = quad * 4 + r;
        Obuf[wg * 4096 + row * 256 + (((nti + quad) & 15) << 4) + l15] = oacc[nti][r];
      }
    if (l15 == 0) {
#pragma unroll
      for (int r = 0; r < 4; ++r) Lb[wg * 16 + quad * 4 + r] = oL[r];
    }
  }
  __syncthreads();
  if (g == 0) {
    float ls[4];
#pragma unroll
    for (int r = 0; r < 4; ++r) ls[r] = Lb[wg * 16 + quad * 4 + r];
#pragma unroll
    for (int nti = 0; nti < 16; ++nti)
#pragma unroll
      for (int r = 0; r < 4; ++r) {
        int row = quad * 4 + r;
        oacc[nti][r] += Obuf[wg * 4096 + row * 256 + (((nti + quad) & 15) << 4) + l15];
      }
    float li[4];
#pragma unroll
    for (int r = 0; r < 4; ++r)
      li[r] = 1.0f / (__shfl(oL[r], lane & 48) + ls[r]);
#pragma unroll
    for (int nti = 0; nti < 16; ++nti) {
      const int gcol = nti * 16 + l15;
#pragma unroll
      for (int r = 0; r < 4; ++r) {
        const int grow = gib + wg * 16 + quad * 4 + r;
        AXw[(size_t)grow * 512 + gcol] = f2bf(oacc[nti][r] * li[r]);
      }
    }
  }
}

// ---------------------------------------------------------------------------
// k2: out_pre = AX @ WC^T  (M=16384, N=256, K=512) == agg@w_att^T + x@w_res^T.
// Block tile 128x64, 4 waves (wave tile 64x32), BK=64, grid 512.
// Epilogue: per-column BN partial sums from acc regs (shfl + LDS + atomics).
// ---------------------------------------------------------------------------
__global__ __launch_bounds__(256, 2) void k2_gemm(const unsigned short* __restrict__ AX,
                                                  const unsigned short* __restrict__ WC,
                                                  float* __restrict__ out,
                                                  float* __restrict__ sums) {
  __shared__ unsigned short As[128 * 72];
  __shared__ unsigned short Bs[64 * 72];
  __shared__ float cs[64], cq[64];
  const int t = threadIdx.x;
  const int w = t >> 6, lane = t & 63, l15 = lane & 15, quad = lane >> 4;
  const int m0 = (blockIdx.x >> 2) * 128, n0 = (blockIdx.x & 3) * 64;
  if (t < 64) { cs[t] = 0.f; cq[t] = 0.f; }

  const f32x4 fz = {0.f, 0.f, 0.f, 0.f};
  f32x4 acc[4][2];
#pragma unroll
  for (int i = 0; i < 4; ++i) { acc[i][0] = fz; acc[i][1] = fz; }

  for (int kk = 0; kk < 512; kk += 64) {
    __syncthreads();
#pragma unroll
    for (int q = 0; q < 4; ++q) {            // A: 128 rows x 64 k
      int idx = t + q * 256;
      int row = idx >> 3, koff = (idx & 7) * 8;
      *(uint4*)&As[row * 72 + koff] = *(const uint4*)(AX + (size_t)(m0 + row) * 512 + kk + koff);
    }
#pragma unroll
    for (int q = 0; q < 2; ++q) {            // B: 64 rows x 64 k
      int idx = t + q * 256;
      int row = idx >> 3, koff = (idx & 7) * 8;
      *(uint4*)&Bs[row * 72 + koff] = *(const uint4*)(WC + (size_t)(n0 + row) * 512 + kk + koff);
    }
    __syncthreads();
#pragma unroll
    for (int kc = 0; kc < 2; ++kc) {
      bf16x8 b0 = *(const bf16x8*)&Bs[((w >> 1) * 32 + l15) * 72 + kc * 32 + quad * 8];
      bf16x8 b1 = *(const bf16x8*)&Bs[((w >> 1) * 32 + 16 + l15) * 72 + kc * 32 + quad * 8];
#pragma unroll
      for (int mt = 0; mt < 4; ++mt) {
        bf16x8 af = *(const bf16x8*)&As[((w & 1) * 64 + mt * 16 + l15) * 72 + kc * 32 + quad * 8];
        acc[mt][0] = MFMA16(af, b0, acc[mt][0]);
        acc[mt][1] = MFMA16(af, b1, acc[mt][1]);
      }
    }
  }
#pragma unroll
  for (int mt = 0; mt < 4; ++mt)
#pragma unroll
    for (int nt = 0; nt < 2; ++nt)
#pragma unroll
      for (int r = 0; r < 4; ++r) {
        int grow = m0 + (w & 1) * 64 + mt * 16 + quad * 4 + r;
        int gcol = n0 + (w >> 1) * 32 + nt * 16 + l15;
        out[(size_t)grow * 256 + gcol] = acc[mt][nt][r];
      }
  // ---- fused BN partial stats: sum / sumsq per column ----
#pragma unroll
  for (int nt = 0; nt < 2; ++nt) {
    float a = 0.f, b2 = 0.f;
#pragma unroll
    for (int mt = 0; mt < 4; ++mt)
#pragma unroll
      for (int r = 0; r < 4; ++r) {
        float v = acc[mt][nt][r];
        a += v; b2 += v * v;
      }
    a += __shfl_xor(a, 16);  a += __shfl_xor(a, 32);
    b2 += __shfl_xor(b2, 16); b2 += __shfl_xor(b2, 32);
    if (quad == 0) {
      int ci = (w >> 1) * 32 + nt * 16 + l15;
      atomicAdd(&cs[ci], a);
      atomicAdd(&cq[ci], b2);
    }
  }
  __syncthreads();
  if (t < 64) {
    atomicAdd(&sums[n0 + t], cs[t]);
    atomicAdd(&sums[256 + n0 + t], cq[t]);
  }
}

// ---------------------------------------------------------------------------
// k4: BatchNorm (biased var) + SELU, in place on d_out.
// ---------------------------------------------------------------------------
__global__ __launch_bounds__(256) void k4_bn_selu(float* __restrict__ out,
                                                  const float* __restrict__ sums,
                                                  const float* __restrict__ gamma,
                                                  const float* __restrict__ beta) {
  int f = (blockIdx.x * 256 + threadIdx.x) * 8;
  int c = f & 255;
  const float inv_m = 1.0f / 16384.0f;
  float4 v0 = *(const float4*)(out + f);
  float4 v1 = *(const float4*)(out + f + 4);
  float vv[8] = {v0.x, v0.y, v0.z, v0.w, v1.x, v1.y, v1.z, v1.w};
#pragma unroll
  for (int k = 0; k < 8; ++k) {
    int ch = c + k;
    float mean = sums[ch] * inv_m;
    float var = sums[256 + ch] * inv_m - mean * mean;
    float y = (vv[k] - mean) * rsqrtf(var + BN_EPS) * gamma[ch] + beta[ch];
    float yc = fminf(fmaxf(y, -10.f), 10.f);
    float r = (y > 0.f) ? y : (SELU_ALPHA * (expf(yc) - 1.0f));
    vv[k] = SELU_SCALE * r;
  }
  float4 o0 = {vv[0], vv[1], vv[2], vv[3]};
  float4 o1 = {vv[4], vv[5], vv[6], vv[7]};
  *(float4*)(out + f) = o0;
  *(float4*)(out + f + 4) = o1;
}

// ---------------------------------------------------------------------------
extern "C" void kernel_launch(void* const* d_in, const int* in_sizes, int n_in,
                              void* d_out, int out_size, void* d_ws, size_t ws_size,
                              hipStream_t stream) {
  const float* x     = (const float*)d_in[0];
  const float* w_map = (const float*)d_in[1];
  const float* w_att = (const float*)d_in[2];
  const float* w_res = (const float*)d_in[3];
  const float* gamma = (const float*)d_in[4];
  const float* beta  = (const float*)d_in[5];
  float* out = (float*)d_out;

  // ws layout (~24.3 MB): AX 16MB | Xt 8MB | WC 256KB | sums 2KB
  unsigned short* AX = (unsigned short*)d_ws;
  unsigned short* Xt = AX + (size_t)ROWS * 512;
  unsigned short* WC = Xt + (size_t)NB * 256 * 2048;
  float* sums = (float*)(WC + 256 * 512);

  k0_prep<<<256, 256, 0, stream>>>(x, AX, Xt);
  k0_wc<<<64, 256, 0, stream>>>(w_att, w_res, WC, sums);
  k1_attn<<<256, 512, 0, stream>>>(w_map, AX, Xt, AX);
  k2_gemm<<<512, 256, 0, stream>>>(AX, WC, out, sums);
  k4_bn_selu<<<2048, 256, 0, stream>>>(out, sums, gamma, beta);
}